// Round 1
// baseline (982.162 us; speedup 1.0000x reference)
//
#include <hip/hip_runtime.h>
#include <math.h>

#define M_CELLS 3872
#define NPIX 16384   // 128*128

// ---- workspace layout (bytes) ----
static constexpr size_t OFF_KF   = 0;                                   // float[3872*128] gathered kernels
static constexpr size_t OFF_SC   = OFF_KF + (size_t)M_CELLS*128*4;      // float[3872] scores
static constexpr size_t OFF_SM   = OFF_SC + (size_t)M_CELLS*4;          // float[3872] sum_masks
static constexpr size_t OFF_CS   = OFF_SM + (size_t)M_CELLS*4;          // float[3872] cscores
static constexpr size_t OFF_BIT  = OFF_CS + (size_t)M_CELLS*4;          // u64[3872*256] mask bitsets
static constexpr size_t OFF_SPP  = OFF_BIT + (size_t)M_CELLS*256*8;     // float[64*3872] partial sumprob
static constexpr size_t OFF_TIDX = OFF_SPP + (size_t)64*M_CELLS*4;      // int[512] top500 idx
static constexpr size_t OFF_TSC  = OFF_TIDX + 512*4;                    // float[512] top500 scores
static constexpr size_t OFF_SMT  = OFF_TSC + 512*4;                     // float[512] sum_masks of top500
static constexpr size_t OFF_IOU  = OFF_SMT + 512*4;                     // float[500*500]
static constexpr size_t OFF_COMP = OFF_IOU + (size_t)500*500*4;         // float[512]
static constexpr size_t OFF_NMS  = OFF_COMP + 512*4;                    // float[512]
static constexpr size_t OFF_SEL  = OFF_NMS + 512*4;                     // int[32]
static constexpr size_t OFF_SELP = OFF_SEL + 32*4;                      // float[30*16384]
static constexpr size_t WS_NEED  = OFF_SELP + (size_t)30*NPIX*4;        // ~13.3 MB

// ---- K0: gather kernels (1,E,g,g)->kf[m][e], scores ----
__global__ __launch_bounds__(256) void k0_gather(
    const float* __restrict__ c0,const float* __restrict__ c1,const float* __restrict__ c2,
    const float* __restrict__ c3,const float* __restrict__ c4,
    const float* __restrict__ w0,const float* __restrict__ w1,const float* __restrict__ w2,
    const float* __restrict__ w3,const float* __restrict__ w4,
    float* __restrict__ kf, float* __restrict__ scores) {
  int t = blockIdx.x*256 + threadIdx.x;
  int m = t >> 7, e = t & 127;
  const float* kl; const float* cl; int off, g;
  if (m < 1600)      { kl=w0; cl=c0; off=0;    g=40; }
  else if (m < 2896) { kl=w1; cl=c1; off=1600; g=36; }
  else if (m < 3472) { kl=w2; cl=c2; off=2896; g=24; }
  else if (m < 3728) { kl=w3; cl=c3; off=3472; g=16; }
  else               { kl=w4; cl=c4; off=3728; g=12; }
  int c = m - off;
  kf[t] = kl[e*g*g + c];
  if (e == 0) scores[m] = cl[c];
}

// ---- K1: mask GEMM + sigmoid + ballot bitset + partial prob sums ----
// grid (64 pixel tiles, 121 cell tiles), block 256. 32 cells x 256 px per block.
__global__ __launch_bounds__(256, 6) void k1_gemm(
    const float* __restrict__ kf, const float* __restrict__ seg,
    unsigned long long* __restrict__ bits, float* __restrict__ spp) {
  int tid = threadIdx.x;
  int p  = blockIdx.x*256 + tid;
  int c0 = blockIdx.y*32;
  float acc[32];
  #pragma unroll
  for (int c=0;c<32;c++) acc[c]=0.f;
  for (int ch=0; ch<8; ch++) {
    float s[16];
    #pragma unroll
    for (int e=0;e<16;e++) s[e] = seg[(ch*16+e)*NPIX + p];
    #pragma unroll
    for (int c=0;c<32;c++) {
      float a=0.f;
      #pragma unroll
      for (int e=0;e<16;e++) a = fmaf(kf[(c0+c)*128 + ch*16 + e], s[e], a);  // uniform addr -> s_load
      acc[c] += a;
    }
  }
  int wv = tid>>6, ln = tid&63;
  __shared__ float wsum[32][4];
  #pragma unroll
  for (int c=0;c<32;c++) {
    float logit = acc[c];
    bool msk = logit > 0.f;
    unsigned long long bal = __ballot(msk);
    float pr = msk ? __fdividef(1.f, 1.f + __expf(-logit)) : 0.f;
    #pragma unroll
    for (int o=32;o>0;o>>=1) pr += __shfl_down(pr, o);
    if (ln==0) {
      bits[(size_t)(c0+c)*256 + blockIdx.x*4 + wv] = bal;
      wsum[c][wv] = pr;
    }
  }
  __syncthreads();
  if (tid < 32)
    spp[(size_t)blockIdx.x*M_CELLS + c0 + tid] = wsum[tid][0]+wsum[tid][1]+wsum[tid][2]+wsum[tid][3];
}

// ---- K2: per-cell sum_masks (popcount), seg_score, cscore ----
__global__ __launch_bounds__(256) void k2_cscore(
    const unsigned long long* __restrict__ bits, const float* __restrict__ spp,
    const float* __restrict__ scores, float* __restrict__ summ, float* __restrict__ cs) {
  int cell = blockIdx.x*4 + (threadIdx.x>>6);
  int ln = threadIdx.x & 63;
  const unsigned long long* row = bits + (size_t)cell*256;
  int cnt = 0;
  #pragma unroll
  for (int k=0;k<4;k++) cnt += __popcll(row[ln + 64*k]);
  float sp = spp[(size_t)ln*M_CELLS + cell];
  #pragma unroll
  for (int o=32;o>0;o>>=1) { cnt += __shfl_down(cnt,o); sp += __shfl_down(sp,o); }
  if (ln==0) {
    float smf = (float)cnt;
    float sc = scores[cell];
    float strd = (cell<1600)?4.f:(cell<2896)?8.f:(cell<3472)?16.f:(cell<3728)?32.f:64.f;
    bool keep = (sc > 0.3f) && (smf > strd);
    float ss = sp / fmaxf(smf, 1.f);
    summ[cell] = smf;
    cs[cell] = keep ? sc*ss : 0.f;
  }
}

__device__ inline unsigned long long packkey(float v, int i) {
  // v >= 0: float bits are monotone. Descending sort => value desc, index asc (JAX top_k ties).
  return ((unsigned long long)__float_as_uint(v) << 32) | (unsigned)(0xFFFFFFFFu - (unsigned)i);
}

// ---- K3: top-500 of 3872 via bitonic sort of 4096 ----
__global__ __launch_bounds__(1024) void k3_top500(
    const float* __restrict__ cs, const float* __restrict__ summ,
    int* __restrict__ tidx, float* __restrict__ tsc, float* __restrict__ smt) {
  __shared__ unsigned long long key[4096];
  int tid = threadIdx.x;
  for (int i=tid;i<4096;i+=1024) key[i] = (i < M_CELLS) ? packkey(cs[i], i) : 0ULL;
  __syncthreads();
  for (int size=2; size<=4096; size<<=1) {
    for (int st=size>>1; st>0; st>>=1) {
      for (int i=tid;i<4096;i+=1024) {
        int pp = i ^ st;
        if (pp > i) {
          unsigned long long a=key[i], b=key[pp];
          bool desc = ((i & size) == 0);
          if (desc ? (a<b) : (a>b)) { key[i]=b; key[pp]=a; }
        }
      }
      __syncthreads();
    }
  }
  if (tid < 512) {
    if (tid < 500) {
      unsigned long long k = key[tid];
      int idx = (int)(0xFFFFFFFFu - (unsigned)(k & 0xFFFFFFFFull));
      tidx[tid] = idx;
      tsc[tid] = __uint_as_float((unsigned)(k>>32));
      smt[tid] = summ[idx];
    } else { tidx[tid]=0; tsc[tid]=0.f; smt[tid]=0.f; }
  }
}

// ---- K4: pairwise mask IoU via bitset AND+popcount, triu(k=1) ----
// grid 32x32 tiles of 16x16 pairs; bitset staged in LDS in two K-halves.
__global__ __launch_bounds__(256) void k4_iou(
    const unsigned long long* __restrict__ bits, const int* __restrict__ tidx,
    const float* __restrict__ smt, float* __restrict__ iou) {
  int ti = blockIdx.y, tj = blockIdx.x;
  int tid = threadIdx.x;
  int ty = tid>>4, tx = tid&15;
  int i = ti*16+ty, j = tj*16+tx;
  if (ti > tj) { if (i<500 && j<500) iou[i*500+j] = 0.f; return; }
  __shared__ unsigned long long A[16][130];  // +2 pad: conflict-free
  __shared__ unsigned long long B[16][130];
  __shared__ float sa[16], sb[16];
  if (tid<16) sa[tid] = (ti*16+tid<500) ? smt[ti*16+tid] : 0.f;
  else if (tid<32) sb[tid-16] = (tj*16+tid-16<500) ? smt[tj*16+tid-16] : 0.f;
  int inter = 0;
  for (int half=0; half<2; half++) {
    __syncthreads();
    for (int t=tid;t<2048;t+=256) {
      int r=t>>7, k=t&127;
      int ii = ti*16+r; A[r][k] = (ii<500) ? bits[(size_t)tidx[ii]*256 + half*128 + k] : 0ULL;
      int jj = tj*16+r; B[r][k] = (jj<500) ? bits[(size_t)tidx[jj]*256 + half*128 + k] : 0ULL;
    }
    __syncthreads();
    for (int k=0;k<128;k++) inter += __popcll(A[ty][k] & B[tx][k]);
  }
  if (i<500 && j<500) {
    float fi = (float)inter;
    float un = sa[ty] + sb[tx] - fi;
    iou[i*500+j] = (i<j) ? fi / fmaxf(un, 1.f) : 0.f;
  }
}

// ---- K5: comp[j] = max_i iou[i][j] ----
__global__ __launch_bounds__(512) void k5_comp(const float* __restrict__ iou, float* __restrict__ comp) {
  int j = threadIdx.x;
  float m = 0.f;
  if (j < 500) for (int i=0;i<500;i++) m = fmaxf(m, iou[i*500+j]);
  comp[j] = m;
}

// ---- K6: decay_coeff + nms score threshold ----
__global__ __launch_bounds__(512) void k6_decay(
    const float* __restrict__ iou, const float* __restrict__ comp,
    const float* __restrict__ tsc, float* __restrict__ nms) {
  int j = threadIdx.x;
  float out = 0.f;
  if (j < 500) {
    float t = -1e30f;
    for (int i=0;i<500;i++) {
      float v = iou[i*500+j]; float c = comp[i];
      t = fmaxf(t, v*v - c*c);
    }
    float s = tsc[j] * __expf(-2.f*t);
    out = (s >= 0.05f) ? s : 0.f;
  }
  nms[j] = out;
}

// ---- K7: top-30 of 500, write final_scores + vis, select cells ----
__global__ __launch_bounds__(256) void k7_top30(
    const float* __restrict__ nms, const int* __restrict__ tidx,
    int* __restrict__ sel, float* __restrict__ out) {
  __shared__ unsigned long long key[512];
  int tid = threadIdx.x;
  for (int i=tid;i<512;i+=256) key[i] = (i<500) ? packkey(nms[i], i) : 0ULL;
  __syncthreads();
  for (int size=2; size<=512; size<<=1) {
    for (int st=size>>1; st>0; st>>=1) {
      for (int i=tid;i<512;i+=256) {
        int pp = i ^ st;
        if (pp > i) {
          unsigned long long a=key[i], b=key[pp];
          bool desc = ((i & size) == 0);
          if (desc ? (a<b) : (a>b)) { key[i]=b; key[pp]=a; }
        }
      }
      __syncthreads();
    }
  }
  if (tid < 30) {
    unsigned long long k = key[tid];
    int j = (int)(0xFFFFFFFFu - (unsigned)(k & 0xFFFFFFFFull));
    float v = __uint_as_float((unsigned)(k>>32));
    out[120+tid] = v;                       // final_scores
    out[150+tid] = (v > 0.3f) ? 1.f : 0.f;  // vis
    sel[tid] = tidx[j];
  }
}

// ---- K8: recompute probs for the 30 selected masks ----
__global__ __launch_bounds__(256) void k8_selp(
    const float* __restrict__ kf, const float* __restrict__ seg,
    const int* __restrict__ sel, float* __restrict__ selp) {
  int msk = blockIdx.y;
  int p = blockIdx.x*256 + threadIdx.x;
  int cell = sel[msk];
  const float* kr = kf + (size_t)cell*128;
  float a0=0.f,a1=0.f,a2=0.f,a3=0.f;
  #pragma unroll
  for (int e=0;e<128;e+=4) {
    a0 = fmaf(kr[e+0], seg[(e+0)*NPIX+p], a0);
    a1 = fmaf(kr[e+1], seg[(e+1)*NPIX+p], a1);
    a2 = fmaf(kr[e+2], seg[(e+2)*NPIX+p], a2);
    a3 = fmaf(kr[e+3], seg[(e+3)*NPIX+p], a3);
  }
  float logit = (a0+a1)+(a2+a3);
  selp[(size_t)msk*NPIX + p] = __fdividef(1.f, 1.f + __expf(-logit));
}

// ---- K9: bilinear upsample 128->512 (half-pixel, clamp), occupancy -> bbox ----
__global__ __launch_bounds__(1024) void k9_bbox(const float* __restrict__ selp, float* out) {
  int msk = blockIdx.x;
  const float* mp = selp + (size_t)msk*NPIX;
  __shared__ int ax[512], ay[512];
  __shared__ int r0[512], r1[512], r2[512], r3[512];
  int tid = threadIdx.x;
  if (tid < 512) { ax[tid]=0; ay[tid]=0; }
  __syncthreads();
  for (int i=tid; i<512*512; i+=1024) {
    int oy = i>>9, ox = i&511;
    float xf = fminf(fmaxf((ox+0.5f)*0.25f - 0.5f, 0.f), 127.f);
    float yf = fminf(fmaxf((oy+0.5f)*0.25f - 0.5f, 0.f), 127.f);
    int x0 = (int)xf, y0 = (int)yf;
    int x1 = min(x0+1,127), y1 = min(y0+1,127);
    float fx = xf-(float)x0, fy = yf-(float)y0;
    const float* ra = mp + y0*128;
    const float* rb = mp + y1*128;
    float v0 = ra[x0]*(1.f-fx) + ra[x1]*fx;
    float v1 = rb[x0]*(1.f-fx) + rb[x1]*fx;
    float v  = v0*(1.f-fy) + v1*fy;
    if (v > 0.5f) { ax[ox]=1; ay[oy]=1; }
  }
  __syncthreads();
  if (tid<512) {
    r0[tid] = ax[tid] ? tid : 512;
    r1[tid] = ax[tid] ? tid : -1;
    r2[tid] = ay[tid] ? tid : 512;
    r3[tid] = ay[tid] ? tid : -1;
  }
  __syncthreads();
  for (int s=256;s>0;s>>=1) {
    if (tid<s) {
      r0[tid]=min(r0[tid],r0[tid+s]); r1[tid]=max(r1[tid],r1[tid+s]);
      r2[tid]=min(r2[tid],r2[tid+s]); r3[tid]=max(r3[tid],r3[tid+s]);
    }
    __syncthreads();
  }
  if (tid==0) {
    bool vis = out[120+msk] > 0.3f;
    out[msk*4+0] = vis ? (float)r0[0] : 0.f;  // xmin
    out[msk*4+1] = vis ? (float)r2[0] : 0.f;  // ymin
    out[msk*4+2] = vis ? (float)r1[0] : 0.f;  // xmax
    out[msk*4+3] = vis ? (float)r3[0] : 0.f;  // ymax
  }
}

extern "C" void kernel_launch(void* const* d_in, const int* in_sizes, int n_in,
                              void* d_out, int out_size, void* d_ws, size_t ws_size,
                              hipStream_t stream) {
  (void)in_sizes; (void)n_in; (void)out_size;
  if (ws_size < WS_NEED) return;  // workspace too small -> fail loudly (poisoned out)
  // setup_inputs dict order: cate0,kern0,cate1,kern1,...,cate4,kern4,seg_pred
  const float* cate[5]; const float* kern[5];
  for (int i=0;i<5;i++){ cate[i]=(const float*)d_in[2*i]; kern[i]=(const float*)d_in[2*i+1]; }
  const float* seg = (const float*)d_in[10];
  char* ws = (char*)d_ws;
  float* kf      = (float*)(ws+OFF_KF);
  float* scores  = (float*)(ws+OFF_SC);
  float* summ    = (float*)(ws+OFF_SM);
  float* cs      = (float*)(ws+OFF_CS);
  unsigned long long* bits = (unsigned long long*)(ws+OFF_BIT);
  float* spp     = (float*)(ws+OFF_SPP);
  int*   tidx    = (int*)(ws+OFF_TIDX);
  float* tsc     = (float*)(ws+OFF_TSC);
  float* smt     = (float*)(ws+OFF_SMT);
  float* iou     = (float*)(ws+OFF_IOU);
  float* comp    = (float*)(ws+OFF_COMP);
  float* nms     = (float*)(ws+OFF_NMS);
  int*   sel     = (int*)(ws+OFF_SEL);
  float* selp    = (float*)(ws+OFF_SELP);
  float* out     = (float*)d_out;

  k0_gather<<<1936, 256, 0, stream>>>(cate[0],cate[1],cate[2],cate[3],cate[4],
                                      kern[0],kern[1],kern[2],kern[3],kern[4], kf, scores);
  k1_gemm  <<<dim3(64,121), 256, 0, stream>>>(kf, seg, bits, spp);
  k2_cscore<<<968, 256, 0, stream>>>(bits, spp, scores, summ, cs);
  k3_top500<<<1, 1024, 0, stream>>>(cs, summ, tidx, tsc, smt);
  k4_iou   <<<dim3(32,32), 256, 0, stream>>>(bits, tidx, smt, iou);
  k5_comp  <<<1, 512, 0, stream>>>(iou, comp);
  k6_decay <<<1, 512, 0, stream>>>(iou, comp, tsc, nms);
  k7_top30 <<<1, 256, 0, stream>>>(nms, tidx, sel, out);
  k8_selp  <<<dim3(64,30), 256, 0, stream>>>(kf, seg, sel, selp);
  k9_bbox  <<<30, 1024, 0, stream>>>(selp, out);
}

// Round 2
// 527.440 us; speedup vs baseline: 1.8621x; 1.8621x over previous
//
#include <hip/hip_runtime.h>
#include <math.h>

#define M_CELLS 3872
#define M_PAD   3968   // 31 * 128
#define NPIX    16384  // 128*128

typedef _Float16 half8 __attribute__((ext_vector_type(8)));
typedef float f32x4 __attribute__((ext_vector_type(4)));
typedef unsigned int uint4v __attribute__((ext_vector_type(4)));

// ===================== workspace layouts =====================
static constexpr size_t ALN(size_t x){ return (x + 255) & ~(size_t)255; }

// ---- fallback layout (exact round-1 footprint, proven to fit) ----
static constexpr size_t F_KF   = 0;
static constexpr size_t F_SC   = F_KF + (size_t)M_CELLS*128*4;
static constexpr size_t F_SM   = F_SC + (size_t)M_CELLS*4;
static constexpr size_t F_CS   = F_SM + (size_t)M_CELLS*4;
static constexpr size_t F_BIT  = F_CS + (size_t)M_CELLS*4;
static constexpr size_t F_SPP  = F_BIT + (size_t)M_CELLS*256*8;
static constexpr size_t F_TIDX = F_SPP + (size_t)64*M_CELLS*4;
static constexpr size_t F_TSC  = F_TIDX + 512*4;
static constexpr size_t F_SMT  = F_TSC + 512*4;
static constexpr size_t F_IOU  = F_SMT + 512*4;
static constexpr size_t F_COMP = F_IOU + (size_t)500*500*4;
static constexpr size_t F_NMS  = F_COMP + 512*4;
static constexpr size_t F_SEL  = F_NMS + 512*4;
static constexpr size_t F_SELP = F_SEL + 32*4;
static constexpr size_t WS_FB  = F_SELP + (size_t)30*NPIX*4;

// ---- MFMA layout (~25.7 MB) ----
static constexpr size_t B_KF   = 0;
static constexpr size_t B_KFH  = ALN(B_KF  + (size_t)M_PAD*128*4);
static constexpr size_t B_KFL  = ALN(B_KFH + (size_t)M_PAD*128*2);
static constexpr size_t B_SGH  = ALN(B_KFL + (size_t)M_PAD*128*2);
static constexpr size_t B_SGL  = ALN(B_SGH + (size_t)NPIX*128*2);
static constexpr size_t B_SC   = ALN(B_SGL + (size_t)NPIX*128*2);
static constexpr size_t B_SM   = ALN(B_SC + (size_t)M_PAD*4);
static constexpr size_t B_CS   = ALN(B_SM + (size_t)M_PAD*4);
static constexpr size_t B_BIT  = ALN(B_CS + (size_t)M_PAD*4);
static constexpr size_t B_SPP  = ALN(B_BIT + (size_t)M_PAD*256*8);
static constexpr size_t B_TIDX = ALN(B_SPP + (size_t)128*M_PAD*4);
static constexpr size_t B_TSC  = ALN(B_TIDX + 512*4);
static constexpr size_t B_SMT  = ALN(B_TSC + 512*4);
static constexpr size_t B_IOU  = ALN(B_SMT + 512*4);
static constexpr size_t B_COMP = ALN(B_IOU + (size_t)500*500*4);
static constexpr size_t B_NMS  = ALN(B_COMP + 512*4);
static constexpr size_t B_SEL  = ALN(B_NMS + 512*4);
static constexpr size_t B_SELP = ALN(B_SEL + 32*4);
static constexpr size_t WS_MFMA = B_SELP + (size_t)30*NPIX*4;

// ===================== K0: gather kernels + scores (+ optional f16 hi/lo) =====================
__global__ __launch_bounds__(256) void k0_gather(
    const float* __restrict__ c0,const float* __restrict__ c1,const float* __restrict__ c2,
    const float* __restrict__ c3,const float* __restrict__ c4,
    const float* __restrict__ w0,const float* __restrict__ w1,const float* __restrict__ w2,
    const float* __restrict__ w3,const float* __restrict__ w4,
    float* __restrict__ kf, float* __restrict__ scores,
    _Float16* __restrict__ kfh, _Float16* __restrict__ kfl, int writeHL) {
  int t = blockIdx.x*256 + threadIdx.x;
  int m = t >> 7, e = t & 127;
  float v = 0.f, sc = 0.f;
  if (m < M_CELLS) {
    const float* kl; const float* cl; int off, g;
    if (m < 1600)      { kl=w0; cl=c0; off=0;    g=40; }
    else if (m < 2896) { kl=w1; cl=c1; off=1600; g=36; }
    else if (m < 3472) { kl=w2; cl=c2; off=2896; g=24; }
    else if (m < 3728) { kl=w3; cl=c3; off=3472; g=16; }
    else               { kl=w4; cl=c4; off=3728; g=12; }
    int c = m - off;
    v = kl[e*g*g + c];
    sc = cl[c];
  }
  kf[t] = v;
  if (e == 0) scores[m] = sc;
  if (writeHL) {
    _Float16 h = (_Float16)v;
    kfh[t] = h;
    kfl[t] = (_Float16)(v - (float)h);
  }
}

// ===================== K0b: transpose seg -> segT hi/lo f16 [px][k] =====================
__global__ __launch_bounds__(256) void k_segT(const float* __restrict__ seg,
                                              _Float16* __restrict__ sgh,
                                              _Float16* __restrict__ sgl) {
  int px = blockIdx.x*256 + threadIdx.x;  // grid 64
  #pragma unroll 4
  for (int e0=0; e0<128; e0+=8) {
    half8 vh, vl;
    #pragma unroll
    for (int j=0;j<8;j++) {
      float x = seg[(size_t)(e0+j)*NPIX + px];
      _Float16 h = (_Float16)x;
      vh[j] = h;
      vl[j] = (_Float16)(x - (float)h);
    }
    *(half8*)&sgh[(size_t)px*128 + e0] = vh;
    *(half8*)&sgl[(size_t)px*128 + e0] = vl;
  }
}

// ===================== K1 (fallback): fp32 vector GEMM (round-1 proven) =====================
__global__ __launch_bounds__(256, 6) void k1_gemm(
    const float* __restrict__ kf, const float* __restrict__ seg,
    unsigned long long* __restrict__ bits, float* __restrict__ spp) {
  int tid = threadIdx.x;
  int p  = blockIdx.x*256 + tid;
  int c0 = blockIdx.y*32;
  float acc[32];
  #pragma unroll
  for (int c=0;c<32;c++) acc[c]=0.f;
  for (int ch=0; ch<8; ch++) {
    float s[16];
    #pragma unroll
    for (int e=0;e<16;e++) s[e] = seg[(size_t)(ch*16+e)*NPIX + p];
    #pragma unroll
    for (int c=0;c<32;c++) {
      float a=0.f;
      #pragma unroll
      for (int e=0;e<16;e++) a = fmaf(kf[(size_t)(c0+c)*128 + ch*16 + e], s[e], a);
      acc[c] += a;
    }
  }
  int wv = tid>>6, ln = tid&63;
  __shared__ float wsum[32][4];
  #pragma unroll
  for (int c=0;c<32;c++) {
    float logit = acc[c];
    bool msk = logit > 0.f;
    unsigned long long bal = __ballot(msk);
    float pr = msk ? __fdividef(1.f, 1.f + __expf(-logit)) : 0.f;
    #pragma unroll
    for (int o=32;o>0;o>>=1) pr += __shfl_down(pr, o);
    if (ln==0) {
      bits[(size_t)(c0+c)*256 + blockIdx.x*4 + wv] = bal;
      wsum[c][wv] = pr;
    }
  }
  __syncthreads();
  if (tid < 32)
    spp[(size_t)blockIdx.x*M_CELLS + c0 + tid] = wsum[tid][0]+wsum[tid][1]+wsum[tid][2]+wsum[tid][3];
}

// ===================== K1 (MFMA): f16 hi/lo split, 3 products =====================
// block = 128 cells x 128 px; 4 waves as 2x2 of 64x64 wave-tiles; K=128 in 4 steps of 32.
// Verified layouts (16x16x32): A[m=lane&15][k=(lane>>4)*8+j]; B[k=(lane>>4)*8+j][n=lane&15];
// C/D col=lane&15, row=(lane>>4)*4+reg.
__global__ __launch_bounds__(256, 3) void k1_mfma(
    const _Float16* __restrict__ kfh, const _Float16* __restrict__ kfl,
    const _Float16* __restrict__ sgh, const _Float16* __restrict__ sgl,
    unsigned long long* __restrict__ bits, float* __restrict__ spp) {
  __shared__ char lds[32768];   // A frags 16KB | B frags 16KB (frag-ordered, lane-linear)
  const int tid  = threadIdx.x;
  const int lane = tid & 63;
  const int wave = tid >> 6;
  const int wr = wave >> 1, wc = wave & 1;
  const int mbase = blockIdx.x * 128;
  const int nbase = blockIdx.y * 128;

  f32x4 acc[4][4];
  #pragma unroll
  for (int a=0;a<4;a++)
    #pragma unroll
    for (int b=0;b<4;b++) acc[a][b] = (f32x4){0.f,0.f,0.f,0.f};

  for (int ks=0; ks<4; ks++) {
    // stage 1024 A-pieces + 1024 B-pieces of 16B, frag-ordered: piece p -> tile mn=p>>7, h=(p>>6)&1, ln=p&63
    #pragma unroll
    for (int i=0;i<4;i++) {
      int p  = i*256 + tid;
      int mn = p >> 7;
      int h  = (p >> 6) & 1;
      int ln = p & 63;
      size_t roff = (size_t)(mn*16 + (ln & 15)) * 128 + ks*32 + (ln>>4)*8;
      const _Float16* sa = (h ? kfl : kfh) + (size_t)mbase*128 + roff;
      const _Float16* sb = (h ? sgl : sgh) + (size_t)nbase*128 + roff;
      *(uint4v*)&lds[p*16]         = *(const uint4v*)sa;
      *(uint4v*)&lds[16384 + p*16] = *(const uint4v*)sb;
    }
    __syncthreads();
    half8 ah[4], al[4];
    #pragma unroll
    for (int mt=0; mt<4; mt++) {
      int m = wr*4 + mt;
      ah[mt] = *(const half8*)&lds[(m*2+0)*1024 + lane*16];
      al[mt] = *(const half8*)&lds[(m*2+1)*1024 + lane*16];
    }
    #pragma unroll
    for (int nt=0; nt<4; nt++) {
      int n = wc*4 + nt;
      half8 bh = *(const half8*)&lds[16384 + (n*2+0)*1024 + lane*16];
      half8 bl = *(const half8*)&lds[16384 + (n*2+1)*1024 + lane*16];
      #pragma unroll
      for (int mt=0; mt<4; mt++) {
        acc[mt][nt] = __builtin_amdgcn_mfma_f32_16x16x32_f16(ah[mt], bh, acc[mt][nt], 0, 0, 0);
        acc[mt][nt] = __builtin_amdgcn_mfma_f32_16x16x32_f16(ah[mt], bl, acc[mt][nt], 0, 0, 0);
        acc[mt][nt] = __builtin_amdgcn_mfma_f32_16x16x32_f16(al[mt], bh, acc[mt][nt], 0, 0, 0);
      }
    }
    __syncthreads();
  }

  // epilogue: ballots -> u64 mask words; sigmoid sums -> per-(nchunk,cell) partials
  const int q = lane >> 4, mm = lane & 15;
  const int wordIdx = blockIdx.y*2 + wc;   // 64-px-aligned word this wave owns
  float* ldsf = (float*)lds;
  #pragma unroll
  for (int mt=0; mt<4; mt++) {
    #pragma unroll
    for (int reg=0; reg<4; reg++) {
      unsigned long long bal[4];
      float ps = 0.f;
      #pragma unroll
      for (int nt=0; nt<4; nt++) {
        float lg = acc[mt][nt][reg];
        bal[nt] = __ballot(lg > 0.f);
        if (lg > 0.f) ps += __fdividef(1.f, 1.f + __expf(-lg));
      }
      ps += __shfl_xor(ps, 1); ps += __shfl_xor(ps, 2);
      ps += __shfl_xor(ps, 4); ps += __shfl_xor(ps, 8);
      if (mm == 0) {
        int cl = wr*64 + mt*16 + q*4 + reg;   // 0..127 cell-in-block
        unsigned long long wd = 0;
        #pragma unroll
        for (int nt=0; nt<4; nt++)
          wd |= ((bal[nt] >> (q*16)) & 0xFFFFull) << (nt*16);
        bits[(size_t)(mbase + cl)*256 + wordIdx] = wd;
        ldsf[cl*2 + wc] = ps;   // combine the two px-halves below
      }
    }
  }
  __syncthreads();
  if (tid < 128)
    spp[(size_t)blockIdx.y*M_PAD + mbase + tid] = ldsf[tid*2] + ldsf[tid*2+1];
}

// ===================== K2: sum_masks (popcount) + seg_score + cscore =====================
__global__ __launch_bounds__(256) void k2_cscore(
    const unsigned long long* __restrict__ bits, const float* __restrict__ spp,
    const float* __restrict__ scores, float* __restrict__ summ, float* __restrict__ cs,
    int nparts, int mp) {
  int cell = blockIdx.x*4 + (threadIdx.x>>6);
  int ln = threadIdx.x & 63;
  const unsigned long long* row = bits + (size_t)cell*256;
  int cnt = 0;
  #pragma unroll
  for (int k=0;k<4;k++) cnt += __popcll(row[ln + 64*k]);
  float sp = 0.f;
  for (int i=ln; i<nparts; i+=64) sp += spp[(size_t)i*mp + cell];
  #pragma unroll
  for (int o=32;o>0;o>>=1) { cnt += __shfl_down(cnt,o); sp += __shfl_down(sp,o); }
  if (ln==0) {
    float smf = (float)cnt;
    float sc = scores[cell];
    float strd = (cell<1600)?4.f:(cell<2896)?8.f:(cell<3472)?16.f:(cell<3728)?32.f:64.f;
    bool keep = (sc > 0.3f) && (smf > strd);
    float ss = sp / fmaxf(smf, 1.f);
    summ[cell] = smf;
    cs[cell] = keep ? sc*ss : 0.f;
  }
}

__device__ inline unsigned long long packkey(float v, int i) {
  return ((unsigned long long)__float_as_uint(v) << 32) | (unsigned)(0xFFFFFFFFu - (unsigned)i);
}

// ===================== K3: top-500 of 3872 via bitonic sort =====================
__global__ __launch_bounds__(1024) void k3_top500(
    const float* __restrict__ cs, const float* __restrict__ summ,
    int* __restrict__ tidx, float* __restrict__ tsc, float* __restrict__ smt) {
  __shared__ unsigned long long key[4096];
  int tid = threadIdx.x;
  for (int i=tid;i<4096;i+=1024) key[i] = (i < M_CELLS) ? packkey(cs[i], i) : 0ULL;
  __syncthreads();
  for (int size=2; size<=4096; size<<=1) {
    for (int st=size>>1; st>0; st>>=1) {
      for (int i=tid;i<4096;i+=1024) {
        int pp = i ^ st;
        if (pp > i) {
          unsigned long long a=key[i], b=key[pp];
          bool desc = ((i & size) == 0);
          if (desc ? (a<b) : (a>b)) { key[i]=b; key[pp]=a; }
        }
      }
      __syncthreads();
    }
  }
  if (tid < 512) {
    if (tid < 500) {
      unsigned long long k = key[tid];
      int idx = (int)(0xFFFFFFFFu - (unsigned)(k & 0xFFFFFFFFull));
      tidx[tid] = idx;
      tsc[tid] = __uint_as_float((unsigned)(k>>32));
      smt[tid] = summ[idx];
    } else { tidx[tid]=0; tsc[tid]=0.f; smt[tid]=0.f; }
  }
}

// ===================== K4: pairwise mask IoU via bitset AND+popcount =====================
__global__ __launch_bounds__(256) void k4_iou(
    const unsigned long long* __restrict__ bits, const int* __restrict__ tidx,
    const float* __restrict__ smt, float* __restrict__ iou) {
  int ti = blockIdx.y, tj = blockIdx.x;
  int tid = threadIdx.x;
  int ty = tid>>4, tx = tid&15;
  int i = ti*16+ty, j = tj*16+tx;
  if (ti > tj) { if (i<500 && j<500) iou[i*500+j] = 0.f; return; }
  __shared__ unsigned long long A[16][130];
  __shared__ unsigned long long B[16][130];
  __shared__ float sa[16], sb[16];
  if (tid<16) sa[tid] = (ti*16+tid<500) ? smt[ti*16+tid] : 0.f;
  else if (tid<32) sb[tid-16] = (tj*16+tid-16<500) ? smt[tj*16+tid-16] : 0.f;
  int inter = 0;
  for (int half=0; half<2; half++) {
    __syncthreads();
    for (int t=tid;t<2048;t+=256) {
      int r=t>>7, k=t&127;
      int ii = ti*16+r; A[r][k] = (ii<500) ? bits[(size_t)tidx[ii]*256 + half*128 + k] : 0ULL;
      int jj = tj*16+r; B[r][k] = (jj<500) ? bits[(size_t)tidx[jj]*256 + half*128 + k] : 0ULL;
    }
    __syncthreads();
    for (int k=0;k<128;k++) inter += __popcll(A[ty][k] & B[tx][k]);
  }
  if (i<500 && j<500) {
    float fi = (float)inter;
    float un = sa[ty] + sb[tx] - fi;
    iou[i*500+j] = (i<j) ? fi / fmaxf(un, 1.f) : 0.f;
  }
}

// ===================== K5/K6: soft-NMS =====================
__global__ __launch_bounds__(512) void k5_comp(const float* __restrict__ iou, float* __restrict__ comp) {
  int j = threadIdx.x;
  float m = 0.f;
  if (j < 500) for (int i=0;i<500;i++) m = fmaxf(m, iou[i*500+j]);
  comp[j] = m;
}

__global__ __launch_bounds__(512) void k6_decay(
    const float* __restrict__ iou, const float* __restrict__ comp,
    const float* __restrict__ tsc, float* __restrict__ nms) {
  int j = threadIdx.x;
  float out = 0.f;
  if (j < 500) {
    float t = -1e30f;
    for (int i=0;i<500;i++) {
      float v = iou[i*500+j]; float c = comp[i];
      t = fmaxf(t, v*v - c*c);
    }
    float s = tsc[j] * __expf(-2.f*t);
    out = (s >= 0.05f) ? s : 0.f;
  }
  nms[j] = out;
}

// ===================== K7: top-30 =====================
__global__ __launch_bounds__(256) void k7_top30(
    const float* __restrict__ nms, const int* __restrict__ tidx,
    int* __restrict__ sel, float* __restrict__ out) {
  __shared__ unsigned long long key[512];
  int tid = threadIdx.x;
  for (int i=tid;i<512;i+=256) key[i] = (i<500) ? packkey(nms[i], i) : 0ULL;
  __syncthreads();
  for (int size=2; size<=512; size<<=1) {
    for (int st=size>>1; st>0; st>>=1) {
      for (int i=tid;i<512;i+=256) {
        int pp = i ^ st;
        if (pp > i) {
          unsigned long long a=key[i], b=key[pp];
          bool desc = ((i & size) == 0);
          if (desc ? (a<b) : (a>b)) { key[i]=b; key[pp]=a; }
        }
      }
      __syncthreads();
    }
  }
  if (tid < 30) {
    unsigned long long k = key[tid];
    int j = (int)(0xFFFFFFFFu - (unsigned)(k & 0xFFFFFFFFull));
    float v = __uint_as_float((unsigned)(k>>32));
    out[120+tid] = v;
    out[150+tid] = (v > 0.3f) ? 1.f : 0.f;
    sel[tid] = tidx[j];
  }
}

// ===================== K8: recompute probs for selected masks =====================
__global__ __launch_bounds__(256) void k8_selp(
    const float* __restrict__ kf, const float* __restrict__ seg,
    const int* __restrict__ sel, float* __restrict__ selp) {
  int msk = blockIdx.y;
  int p = blockIdx.x*256 + threadIdx.x;
  int cell = sel[msk];
  const float* kr = kf + (size_t)cell*128;
  float a0=0.f,a1=0.f,a2=0.f,a3=0.f;
  #pragma unroll
  for (int e=0;e<128;e+=4) {
    a0 = fmaf(kr[e+0], seg[(size_t)(e+0)*NPIX+p], a0);
    a1 = fmaf(kr[e+1], seg[(size_t)(e+1)*NPIX+p], a1);
    a2 = fmaf(kr[e+2], seg[(size_t)(e+2)*NPIX+p], a2);
    a3 = fmaf(kr[e+3], seg[(size_t)(e+3)*NPIX+p], a3);
  }
  float logit = (a0+a1)+(a2+a3);
  selp[(size_t)msk*NPIX + p] = __fdividef(1.f, 1.f + __expf(-logit));
}

// ===================== K9: upsample occupancy -> bbox =====================
__global__ __launch_bounds__(1024) void k9_bbox(const float* __restrict__ selp, float* out) {
  int msk = blockIdx.x;
  const float* mp = selp + (size_t)msk*NPIX;
  __shared__ int ax[512], ay[512];
  __shared__ int r0[512], r1[512], r2[512], r3[512];
  int tid = threadIdx.x;
  if (tid < 512) { ax[tid]=0; ay[tid]=0; }
  __syncthreads();
  for (int i=tid; i<512*512; i+=1024) {
    int oy = i>>9, ox = i&511;
    float xf = fminf(fmaxf((ox+0.5f)*0.25f - 0.5f, 0.f), 127.f);
    float yf = fminf(fmaxf((oy+0.5f)*0.25f - 0.5f, 0.f), 127.f);
    int x0 = (int)xf, y0 = (int)yf;
    int x1 = min(x0+1,127), y1 = min(y0+1,127);
    float fx = xf-(float)x0, fy = yf-(float)y0;
    const float* ra = mp + y0*128;
    const float* rb = mp + y1*128;
    float v0 = ra[x0]*(1.f-fx) + ra[x1]*fx;
    float v1 = rb[x0]*(1.f-fx) + rb[x1]*fx;
    float v  = v0*(1.f-fy) + v1*fy;
    if (v > 0.5f) { ax[ox]=1; ay[oy]=1; }
  }
  __syncthreads();
  if (tid<512) {
    r0[tid] = ax[tid] ? tid : 512;
    r1[tid] = ax[tid] ? tid : -1;
    r2[tid] = ay[tid] ? tid : 512;
    r3[tid] = ay[tid] ? tid : -1;
  }
  __syncthreads();
  for (int s=256;s>0;s>>=1) {
    if (tid<s) {
      r0[tid]=min(r0[tid],r0[tid+s]); r1[tid]=max(r1[tid],r1[tid+s]);
      r2[tid]=min(r2[tid],r2[tid+s]); r3[tid]=max(r3[tid],r3[tid+s]);
    }
    __syncthreads();
  }
  if (tid==0) {
    bool vis = out[120+msk] > 0.3f;
    out[msk*4+0] = vis ? (float)r0[0] : 0.f;
    out[msk*4+1] = vis ? (float)r2[0] : 0.f;
    out[msk*4+2] = vis ? (float)r1[0] : 0.f;
    out[msk*4+3] = vis ? (float)r3[0] : 0.f;
  }
}

// ===================== launch =====================
extern "C" void kernel_launch(void* const* d_in, const int* in_sizes, int n_in,
                              void* d_out, int out_size, void* d_ws, size_t ws_size,
                              hipStream_t stream) {
  (void)in_sizes; (void)n_in; (void)out_size;
  if (ws_size < WS_FB) return;
  const float* cate[5]; const float* kern[5];
  for (int i=0;i<5;i++){ cate[i]=(const float*)d_in[2*i]; kern[i]=(const float*)d_in[2*i+1]; }
  const float* seg = (const float*)d_in[10];
  char* ws = (char*)d_ws;
  float* out = (float*)d_out;

  const bool mfma = (ws_size >= WS_MFMA);

  float* kf      = (float*)(ws + (mfma ? B_KF   : F_KF));
  float* scores  = (float*)(ws + (mfma ? B_SC   : F_SC));
  float* summ    = (float*)(ws + (mfma ? B_SM   : F_SM));
  float* cs      = (float*)(ws + (mfma ? B_CS   : F_CS));
  unsigned long long* bits = (unsigned long long*)(ws + (mfma ? B_BIT : F_BIT));
  float* spp     = (float*)(ws + (mfma ? B_SPP  : F_SPP));
  int*   tidx    = (int*)(ws + (mfma ? B_TIDX : F_TIDX));
  float* tsc     = (float*)(ws + (mfma ? B_TSC  : F_TSC));
  float* smt     = (float*)(ws + (mfma ? B_SMT  : F_SMT));
  float* iou     = (float*)(ws + (mfma ? B_IOU  : F_IOU));
  float* comp    = (float*)(ws + (mfma ? B_COMP : F_COMP));
  float* nms     = (float*)(ws + (mfma ? B_NMS  : F_NMS));
  int*   sel     = (int*)(ws + (mfma ? B_SEL  : F_SEL));
  float* selp    = (float*)(ws + (mfma ? B_SELP : F_SELP));

  if (mfma) {
    _Float16* kfh = (_Float16*)(ws + B_KFH);
    _Float16* kfl = (_Float16*)(ws + B_KFL);
    _Float16* sgh = (_Float16*)(ws + B_SGH);
    _Float16* sgl = (_Float16*)(ws + B_SGL);
    k0_gather<<<M_PAD*128/256, 256, 0, stream>>>(cate[0],cate[1],cate[2],cate[3],cate[4],
                                      kern[0],kern[1],kern[2],kern[3],kern[4],
                                      kf, scores, kfh, kfl, 1);
    k_segT   <<<NPIX/256, 256, 0, stream>>>(seg, sgh, sgl);
    k1_mfma  <<<dim3(M_PAD/128, NPIX/128), 256, 0, stream>>>(kfh, kfl, sgh, sgl, bits, spp);
    k2_cscore<<<M_CELLS/4, 256, 0, stream>>>(bits, spp, scores, summ, cs, 128, M_PAD);
  } else {
    k0_gather<<<M_CELLS*128/256, 256, 0, stream>>>(cate[0],cate[1],cate[2],cate[3],cate[4],
                                      kern[0],kern[1],kern[2],kern[3],kern[4],
                                      kf, scores, (_Float16*)ws, (_Float16*)ws, 0);
    k1_gemm  <<<dim3(64,121), 256, 0, stream>>>(kf, seg, bits, spp);
    k2_cscore<<<M_CELLS/4, 256, 0, stream>>>(bits, spp, scores, summ, cs, 64, M_CELLS);
  }
  k3_top500<<<1, 1024, 0, stream>>>(cs, summ, tidx, tsc, smt);
  k4_iou   <<<dim3(32,32), 256, 0, stream>>>(bits, tidx, smt, iou);
  k5_comp  <<<1, 512, 0, stream>>>(iou, comp);
  k6_decay <<<1, 512, 0, stream>>>(iou, comp, tsc, nms);
  k7_top30 <<<1, 256, 0, stream>>>(nms, tidx, sel, out);
  k8_selp  <<<dim3(64,30), 256, 0, stream>>>(kf, seg, sel, selp);
  k9_bbox  <<<30, 1024, 0, stream>>>(selp, out);
}

// Round 3
// 522.653 us; speedup vs baseline: 1.8792x; 1.0092x over previous
//
#include <hip/hip_runtime.h>
#include <math.h>

#define M_CELLS 3872
#define M_PAD   3968   // 31 * 128
#define NPIX    16384  // 128*128

typedef _Float16 half8 __attribute__((ext_vector_type(8)));
typedef float f32x4 __attribute__((ext_vector_type(4)));

// async global->LDS 16B: per-lane global addr, wave-uniform LDS base (+lane*16 in HW)
#define GL2LDS(g, l) __builtin_amdgcn_global_load_lds( \
    (const __attribute__((address_space(1))) unsigned int*)(g), \
    (__attribute__((address_space(3))) unsigned int*)(l), 16, 0, 0)

// ===================== workspace layouts =====================
static constexpr size_t ALN(size_t x){ return (x + 255) & ~(size_t)255; }

// ---- fallback layout (round-1 footprint, proven to fit) ----
static constexpr size_t F_KF   = 0;
static constexpr size_t F_SC   = F_KF + (size_t)M_CELLS*128*4;
static constexpr size_t F_SM   = F_SC + (size_t)M_CELLS*4;
static constexpr size_t F_CS   = F_SM + (size_t)M_CELLS*4;
static constexpr size_t F_BIT  = F_CS + (size_t)M_CELLS*4;
static constexpr size_t F_SPP  = F_BIT + (size_t)M_CELLS*256*8;
static constexpr size_t F_TIDX = F_SPP + (size_t)64*M_CELLS*4;
static constexpr size_t F_TSC  = F_TIDX + 512*4;
static constexpr size_t F_SMT  = F_TSC + 512*4;
static constexpr size_t F_IOU  = F_SMT + 512*4;
static constexpr size_t F_COMP = F_IOU + (size_t)500*500*4;
static constexpr size_t F_NMS  = F_COMP + 512*4;
static constexpr size_t F_SEL  = F_NMS + 512*4;
static constexpr size_t F_SELP = F_SEL + 32*4;
static constexpr size_t WS_FB  = F_SELP + (size_t)30*NPIX*4;

// ---- MFMA layout (~25 MB, <= round-2 footprint which fit) ----
static constexpr size_t B_KF   = 0;                                       // float[M_PAD*128] row-major
static constexpr size_t B_AFR  = ALN(B_KF  + (size_t)M_PAD*128*4);        // frag-ordered A (hi/lo) 2MB
static constexpr size_t B_BFR  = ALN(B_AFR + (size_t)31*4*1024*16);       // frag-ordered B (hi/lo) 8MB
static constexpr size_t B_SC   = ALN(B_BFR + (size_t)128*4*1024*16);
static constexpr size_t B_SM   = ALN(B_SC + (size_t)M_PAD*4);
static constexpr size_t B_CS   = ALN(B_SM + (size_t)M_PAD*4);
static constexpr size_t B_BIT  = ALN(B_CS + (size_t)M_PAD*4);
static constexpr size_t B_SPP  = ALN(B_BIT + (size_t)M_PAD*256*8);
static constexpr size_t B_TIDX = ALN(B_SPP + (size_t)128*M_PAD*4);
static constexpr size_t B_TSC  = ALN(B_TIDX + 512*4);
static constexpr size_t B_SMT  = ALN(B_TSC + 512*4);
static constexpr size_t B_IOU  = ALN(B_SMT + 512*4);
static constexpr size_t B_COMP = ALN(B_IOU + (size_t)500*500*4);
static constexpr size_t B_NMS  = ALN(B_COMP + 512*4);
static constexpr size_t B_SEL  = ALN(B_NMS + 512*4);
static constexpr size_t B_SELP = ALN(B_SEL + 32*4);
static constexpr size_t WS_MFMA = B_SELP + (size_t)30*NPIX*4;

// ===================== K0a: gather kernels + scores, coalesced reads =====================
// t = e*G + c  ->  read kl[t] is fully linear; only the 4B write scatters.
__global__ __launch_bounds__(256) void k0a_gather(
    const float* __restrict__ c0,const float* __restrict__ c1,const float* __restrict__ c2,
    const float* __restrict__ c3,const float* __restrict__ c4,
    const float* __restrict__ w0,const float* __restrict__ w1,const float* __restrict__ w2,
    const float* __restrict__ w3,const float* __restrict__ w4,
    float* __restrict__ kf, float* __restrict__ scores) {
  const int lvl = blockIdx.y;
  const int Gs[5]   = {1600,1296,576,256,144};
  const int offs[5] = {0,1600,2896,3472,3728};
  const int G = Gs[lvl], off = offs[lvl];
  const float* kl = (lvl==0)?w0:(lvl==1)?w1:(lvl==2)?w2:(lvl==3)?w3:w4;
  const float* cl = (lvl==0)?c0:(lvl==1)?c1:(lvl==2)?c2:(lvl==3)?c3:c4;
  int t = blockIdx.x*256 + threadIdx.x;
  if (t >= G*128) return;
  int e = t / G, c = t - e*G;
  kf[(size_t)(off+c)*128 + e] = kl[t];
  if (e == 0) scores[off+c] = cl[c];
}

// ===================== K0b: kf -> frag-ordered A (f16 hi/lo pieces) =====================
// piece P: mblock=P>>12, ks=(P>>10)&3, p=P&1023; mn=p>>7, h=(p>>6)&1, ln=p&63
// data = 8 halves of kf[mblock*128+mn*16+(ln&15)][ks*32+(ln>>4)*8 ..+8], hi or lo part.
__global__ __launch_bounds__(256) void k0b_afrag(const float* __restrict__ kf,
                                                 _Float16* __restrict__ Af) {
  int P = blockIdx.x*256 + threadIdx.x;     // 31*4*1024 = 126976
  int mblock = P >> 12;
  int ks = (P >> 10) & 3;
  int p  = P & 1023;
  int mn = p >> 7, h = (p >> 6) & 1, ln = p & 63;
  int m  = mblock*128 + mn*16 + (ln & 15);
  int kb = ks*32 + (ln >> 4)*8;
  const float* src = kf + (size_t)m*128 + kb;
  half8 o;
  #pragma unroll
  for (int j=0;j<8;j++) {
    float x = src[j];
    _Float16 hi = (_Float16)x;
    o[j] = h ? (_Float16)(x - (float)hi) : hi;
  }
  *(half8*)&Af[(size_t)P*8] = o;
}

// ===================== K0c: seg -> frag-ordered B (f16 hi/lo pieces) =====================
__global__ __launch_bounds__(256) void k0c_bfrag(const float* __restrict__ seg,
                                                 _Float16* __restrict__ Bf) {
  int P = blockIdx.x*256 + threadIdx.x;     // 128*4*1024 = 524288
  int nb = P >> 12;
  int ks = (P >> 10) & 3;
  int p  = P & 1023;
  int mn = p >> 7, h = (p >> 6) & 1, ln = p & 63;
  int px = nb*128 + mn*16 + (ln & 15);
  int kb = ks*32 + (ln >> 4)*8;
  half8 o;
  #pragma unroll
  for (int j=0;j<8;j++) {
    float x = seg[(size_t)(kb+j)*NPIX + px];
    _Float16 hi = (_Float16)x;
    o[j] = h ? (_Float16)(x - (float)hi) : hi;
  }
  *(half8*)&Bf[(size_t)P*8] = o;
}

// ===================== K1 (fallback): fp32 vector GEMM =====================
__global__ __launch_bounds__(256, 6) void k1_gemm(
    const float* __restrict__ kf, const float* __restrict__ seg,
    unsigned long long* __restrict__ bits, float* __restrict__ spp) {
  int tid = threadIdx.x;
  int p  = blockIdx.x*256 + tid;
  int c0 = blockIdx.y*32;
  float acc[32];
  #pragma unroll
  for (int c=0;c<32;c++) acc[c]=0.f;
  for (int ch=0; ch<8; ch++) {
    float s[16];
    #pragma unroll
    for (int e=0;e<16;e++) s[e] = seg[(size_t)(ch*16+e)*NPIX + p];
    #pragma unroll
    for (int c=0;c<32;c++) {
      float a=0.f;
      #pragma unroll
      for (int e=0;e<16;e++) a = fmaf(kf[(size_t)(c0+c)*128 + ch*16 + e], s[e], a);
      acc[c] += a;
    }
  }
  int wv = tid>>6, ln = tid&63;
  __shared__ float wsum[32][4];
  #pragma unroll
  for (int c=0;c<32;c++) {
    float logit = acc[c];
    bool msk = logit > 0.f;
    unsigned long long bal = __ballot(msk);
    float pr = msk ? __fdividef(1.f, 1.f + __expf(-logit)) : 0.f;
    #pragma unroll
    for (int o=32;o>0;o>>=1) pr += __shfl_down(pr, o);
    if (ln==0) {
      bits[(size_t)(c0+c)*256 + blockIdx.x*4 + wv] = bal;
      wsum[c][wv] = pr;
    }
  }
  __syncthreads();
  if (tid < 32)
    spp[(size_t)blockIdx.x*M_CELLS + c0 + tid] = wsum[tid][0]+wsum[tid][1]+wsum[tid][2]+wsum[tid][3];
}

// ===================== K1 (MFMA): frag-ordered async staging + dbuf =====================
// block = 128 cells x 128 px; 4 waves as 2x2 of 64x64; K=128 in 4 steps of 32 (x hi/lo).
// LDS: 2 buffers x (A 16KB | B 16KB). global_load_lds(16B): uniform LDS base + lane*16.
__global__ __launch_bounds__(256, 2) void k1_mfma(
    const _Float16* __restrict__ Af, const _Float16* __restrict__ Bf,
    unsigned long long* __restrict__ bits, float* __restrict__ spp) {
  __shared__ char lds[65536];
  const int tid  = threadIdx.x;
  const int lane = tid & 63;
  const int wave = tid >> 6;
  const int wr = wave >> 1, wc = wave & 1;
  const char* gA = (const char*)Af + (size_t)blockIdx.x*65536;
  const char* gB = (const char*)Bf + (size_t)blockIdx.y*65536;

  f32x4 acc[4][4];
  #pragma unroll
  for (int a=0;a<4;a++)
    #pragma unroll
    for (int b=0;b<4;b++) acc[a][b] = (f32x4){0.f,0.f,0.f,0.f};

  auto issue = [&](int ks, int buf) {
    const char* ga = gA + (size_t)ks*16384;
    const char* gb = gB + (size_t)ks*16384;
    char* la = &lds[buf*32768];
    char* lb = &lds[buf*32768 + 16384];
    #pragma unroll
    for (int i=0;i<4;i++) {
      int grp = i*4 + wave;            // 16 groups of 64 pieces
      int off = grp*1024 + lane*16;
      GL2LDS(ga + off, la + grp*1024);
      GL2LDS(gb + off, lb + grp*1024);
    }
  };

  issue(0, 0);
  for (int ks=0; ks<4; ks++) {
    __syncthreads();                    // drains this buffer's loads (vmcnt at barrier)
    if (ks < 3) issue(ks+1, (ks+1)&1);  // prefetch flies during the MFMAs below
    const char* lb = &lds[(ks&1)*32768];
    half8 ah[4], al[4];
    #pragma unroll
    for (int mt=0; mt<4; mt++) {
      int m = wr*4 + mt;
      ah[mt] = *(const half8*)&lb[(m*2+0)*1024 + lane*16];
      al[mt] = *(const half8*)&lb[(m*2+1)*1024 + lane*16];
    }
    #pragma unroll
    for (int nt=0; nt<4; nt++) {
      int n = wc*4 + nt;
      half8 bh = *(const half8*)&lb[16384 + (n*2+0)*1024 + lane*16];
      half8 bl = *(const half8*)&lb[16384 + (n*2+1)*1024 + lane*16];
      #pragma unroll
      for (int mt=0; mt<4; mt++) {
        acc[mt][nt] = __builtin_amdgcn_mfma_f32_16x16x32_f16(ah[mt], bh, acc[mt][nt], 0, 0, 0);
        acc[mt][nt] = __builtin_amdgcn_mfma_f32_16x16x32_f16(ah[mt], bl, acc[mt][nt], 0, 0, 0);
        acc[mt][nt] = __builtin_amdgcn_mfma_f32_16x16x32_f16(al[mt], bh, acc[mt][nt], 0, 0, 0);
      }
    }
  }
  __syncthreads();   // all compute done before LDS reuse below

  // epilogue: ballots -> u64 words; sigmoid sums -> per-(nblock,cell) partials
  const int q = lane >> 4, mm = lane & 15;
  const int mbase = blockIdx.x * 128;
  const int wordIdx = blockIdx.y*2 + wc;
  float* ldsf = (float*)lds;
  #pragma unroll
  for (int mt=0; mt<4; mt++) {
    #pragma unroll
    for (int reg=0; reg<4; reg++) {
      unsigned long long bal[4];
      float ps = 0.f;
      #pragma unroll
      for (int nt=0; nt<4; nt++) {
        float lg = acc[mt][nt][reg];
        bal[nt] = __ballot(lg > 0.f);
        if (lg > 0.f) ps += __fdividef(1.f, 1.f + __expf(-lg));
      }
      ps += __shfl_xor(ps, 1); ps += __shfl_xor(ps, 2);
      ps += __shfl_xor(ps, 4); ps += __shfl_xor(ps, 8);
      if (mm == 0) {
        int cl = wr*64 + mt*16 + q*4 + reg;
        unsigned long long wd = 0;
        #pragma unroll
        for (int nt=0; nt<4; nt++)
          wd |= ((bal[nt] >> (q*16)) & 0xFFFFull) << (nt*16);
        bits[(size_t)(mbase + cl)*256 + wordIdx] = wd;
        ldsf[cl*2 + wc] = ps;
      }
    }
  }
  __syncthreads();
  if (tid < 128)
    spp[(size_t)blockIdx.y*M_PAD + mbase + tid] = ldsf[tid*2] + ldsf[tid*2+1];
}

// ===================== K2: sum_masks + seg_score + cscore =====================
__global__ __launch_bounds__(256) void k2_cscore(
    const unsigned long long* __restrict__ bits, const float* __restrict__ spp,
    const float* __restrict__ scores, float* __restrict__ summ, float* __restrict__ cs,
    int nparts, int mp) {
  int cell = blockIdx.x*4 + (threadIdx.x>>6);
  int ln = threadIdx.x & 63;
  const unsigned long long* row = bits + (size_t)cell*256;
  int cnt = 0;
  #pragma unroll
  for (int k=0;k<4;k++) cnt += __popcll(row[ln + 64*k]);
  float sp = 0.f;
  for (int i=ln; i<nparts; i+=64) sp += spp[(size_t)i*mp + cell];
  #pragma unroll
  for (int o=32;o>0;o>>=1) { cnt += __shfl_down(cnt,o); sp += __shfl_down(sp,o); }
  if (ln==0) {
    float smf = (float)cnt;
    float sc = scores[cell];
    float strd = (cell<1600)?4.f:(cell<2896)?8.f:(cell<3472)?16.f:(cell<3728)?32.f:64.f;
    bool keep = (sc > 0.3f) && (smf > strd);
    float ss = sp / fmaxf(smf, 1.f);
    summ[cell] = smf;
    cs[cell] = keep ? sc*ss : 0.f;
  }
}

__device__ inline unsigned long long packkey(float v, int i) {
  return ((unsigned long long)__float_as_uint(v) << 32) | (unsigned)(0xFFFFFFFFu - (unsigned)i);
}

// ===================== K3: top-500 of 3872 via bitonic sort =====================
__global__ __launch_bounds__(1024) void k3_top500(
    const float* __restrict__ cs, const float* __restrict__ summ,
    int* __restrict__ tidx, float* __restrict__ tsc, float* __restrict__ smt) {
  __shared__ unsigned long long key[4096];
  int tid = threadIdx.x;
  for (int i=tid;i<4096;i+=1024) key[i] = (i < M_CELLS) ? packkey(cs[i], i) : 0ULL;
  __syncthreads();
  for (int size=2; size<=4096; size<<=1) {
    for (int st=size>>1; st>0; st>>=1) {
      for (int i=tid;i<4096;i+=1024) {
        int pp = i ^ st;
        if (pp > i) {
          unsigned long long a=key[i], b=key[pp];
          bool desc = ((i & size) == 0);
          if (desc ? (a<b) : (a>b)) { key[i]=b; key[pp]=a; }
        }
      }
      __syncthreads();
    }
  }
  if (tid < 512) {
    if (tid < 500) {
      unsigned long long k = key[tid];
      int idx = (int)(0xFFFFFFFFu - (unsigned)(k & 0xFFFFFFFFull));
      tidx[tid] = idx;
      tsc[tid] = __uint_as_float((unsigned)(k>>32));
      smt[tid] = summ[idx];
    } else { tidx[tid]=0; tsc[tid]=0.f; smt[tid]=0.f; }
  }
}

// ===================== K4: pairwise mask IoU via bitset AND+popcount =====================
__global__ __launch_bounds__(256) void k4_iou(
    const unsigned long long* __restrict__ bits, const int* __restrict__ tidx,
    const float* __restrict__ smt, float* __restrict__ iou) {
  int ti = blockIdx.y, tj = blockIdx.x;
  int tid = threadIdx.x;
  int ty = tid>>4, tx = tid&15;
  int i = ti*16+ty, j = tj*16+tx;
  if (ti > tj) { if (i<500 && j<500) iou[i*500+j] = 0.f; return; }
  __shared__ unsigned long long A[16][130];
  __shared__ unsigned long long B[16][130];
  __shared__ float sa[16], sb[16];
  if (tid<16) sa[tid] = (ti*16+tid<500) ? smt[ti*16+tid] : 0.f;
  else if (tid<32) sb[tid-16] = (tj*16+tid-16<500) ? smt[tj*16+tid-16] : 0.f;
  int inter = 0;
  for (int half=0; half<2; half++) {
    __syncthreads();
    for (int t=tid;t<2048;t+=256) {
      int r=t>>7, k=t&127;
      int ii = ti*16+r; A[r][k] = (ii<500) ? bits[(size_t)tidx[ii]*256 + half*128 + k] : 0ULL;
      int jj = tj*16+r; B[r][k] = (jj<500) ? bits[(size_t)tidx[jj]*256 + half*128 + k] : 0ULL;
    }
    __syncthreads();
    for (int k=0;k<128;k++) inter += __popcll(A[ty][k] & B[tx][k]);
  }
  if (i<500 && j<500) {
    float fi = (float)inter;
    float un = sa[ty] + sb[tx] - fi;
    iou[i*500+j] = (i<j) ? fi / fmaxf(un, 1.f) : 0.f;
  }
}

// ===================== K5/K6: soft-NMS =====================
__global__ __launch_bounds__(512) void k5_comp(const float* __restrict__ iou, float* __restrict__ comp) {
  int j = threadIdx.x;
  float m = 0.f;
  if (j < 500) for (int i=0;i<500;i++) m = fmaxf(m, iou[i*500+j]);
  comp[j] = m;
}

__global__ __launch_bounds__(512) void k6_decay(
    const float* __restrict__ iou, const float* __restrict__ comp,
    const float* __restrict__ tsc, float* __restrict__ nms) {
  int j = threadIdx.x;
  float out = 0.f;
  if (j < 500) {
    float t = -1e30f;
    for (int i=0;i<500;i++) {
      float v = iou[i*500+j]; float c = comp[i];
      t = fmaxf(t, v*v - c*c);
    }
    float s = tsc[j] * __expf(-2.f*t);
    out = (s >= 0.05f) ? s : 0.f;
  }
  nms[j] = out;
}

// ===================== K7: top-30 =====================
__global__ __launch_bounds__(256) void k7_top30(
    const float* __restrict__ nms, const int* __restrict__ tidx,
    int* __restrict__ sel, float* __restrict__ out) {
  __shared__ unsigned long long key[512];
  int tid = threadIdx.x;
  for (int i=tid;i<512;i+=256) key[i] = (i<500) ? packkey(nms[i], i) : 0ULL;
  __syncthreads();
  for (int size=2; size<=512; size<<=1) {
    for (int st=size>>1; st>0; st>>=1) {
      for (int i=tid;i<512;i+=256) {
        int pp = i ^ st;
        if (pp > i) {
          unsigned long long a=key[i], b=key[pp];
          bool desc = ((i & size) == 0);
          if (desc ? (a<b) : (a>b)) { key[i]=b; key[pp]=a; }
        }
      }
      __syncthreads();
    }
  }
  if (tid < 30) {
    unsigned long long k = key[tid];
    int j = (int)(0xFFFFFFFFu - (unsigned)(k & 0xFFFFFFFFull));
    float v = __uint_as_float((unsigned)(k>>32));
    out[120+tid] = v;
    out[150+tid] = (v > 0.3f) ? 1.f : 0.f;
    sel[tid] = tidx[j];
  }
}

// ===================== K8: recompute probs for selected masks =====================
__global__ __launch_bounds__(256) void k8_selp(
    const float* __restrict__ kf, const float* __restrict__ seg,
    const int* __restrict__ sel, float* __restrict__ selp) {
  int msk = blockIdx.y;
  int p = blockIdx.x*256 + threadIdx.x;
  int cell = sel[msk];
  const float* kr = kf + (size_t)cell*128;
  float a0=0.f,a1=0.f,a2=0.f,a3=0.f;
  #pragma unroll
  for (int e=0;e<128;e+=4) {
    a0 = fmaf(kr[e+0], seg[(size_t)(e+0)*NPIX+p], a0);
    a1 = fmaf(kr[e+1], seg[(size_t)(e+1)*NPIX+p], a1);
    a2 = fmaf(kr[e+2], seg[(size_t)(e+2)*NPIX+p], a2);
    a3 = fmaf(kr[e+3], seg[(size_t)(e+3)*NPIX+p], a3);
  }
  float logit = (a0+a1)+(a2+a3);
  selp[(size_t)msk*NPIX + p] = __fdividef(1.f, 1.f + __expf(-logit));
}

// ===================== K9: upsample occupancy -> bbox =====================
__global__ __launch_bounds__(1024) void k9_bbox(const float* __restrict__ selp, float* out) {
  int msk = blockIdx.x;
  const float* mp = selp + (size_t)msk*NPIX;
  __shared__ int ax[512], ay[512];
  __shared__ int r0[512], r1[512], r2[512], r3[512];
  int tid = threadIdx.x;
  if (tid < 512) { ax[tid]=0; ay[tid]=0; }
  __syncthreads();
  for (int i=tid; i<512*512; i+=1024) {
    int oy = i>>9, ox = i&511;
    float xf = fminf(fmaxf((ox+0.5f)*0.25f - 0.5f, 0.f), 127.f);
    float yf = fminf(fmaxf((oy+0.5f)*0.25f - 0.5f, 0.f), 127.f);
    int x0 = (int)xf, y0 = (int)yf;
    int x1 = min(x0+1,127), y1 = min(y0+1,127);
    float fx = xf-(float)x0, fy = yf-(float)y0;
    const float* ra = mp + y0*128;
    const float* rb = mp + y1*128;
    float v0 = ra[x0]*(1.f-fx) + ra[x1]*fx;
    float v1 = rb[x0]*(1.f-fx) + rb[x1]*fx;
    float v  = v0*(1.f-fy) + v1*fy;
    if (v > 0.5f) { ax[ox]=1; ay[oy]=1; }
  }
  __syncthreads();
  if (tid<512) {
    r0[tid] = ax[tid] ? tid : 512;
    r1[tid] = ax[tid] ? tid : -1;
    r2[tid] = ay[tid] ? tid : 512;
    r3[tid] = ay[tid] ? tid : -1;
  }
  __syncthreads();
  for (int s=256;s>0;s>>=1) {
    if (tid<s) {
      r0[tid]=min(r0[tid],r0[tid+s]); r1[tid]=max(r1[tid],r1[tid+s]);
      r2[tid]=min(r2[tid],r2[tid+s]); r3[tid]=max(r3[tid],r3[tid+s]);
    }
    __syncthreads();
  }
  if (tid==0) {
    bool vis = out[120+msk] > 0.3f;
    out[msk*4+0] = vis ? (float)r0[0] : 0.f;
    out[msk*4+1] = vis ? (float)r2[0] : 0.f;
    out[msk*4+2] = vis ? (float)r1[0] : 0.f;
    out[msk*4+3] = vis ? (float)r3[0] : 0.f;
  }
}

// ===================== launch =====================
extern "C" void kernel_launch(void* const* d_in, const int* in_sizes, int n_in,
                              void* d_out, int out_size, void* d_ws, size_t ws_size,
                              hipStream_t stream) {
  (void)in_sizes; (void)n_in; (void)out_size;
  if (ws_size < WS_FB) return;
  const float* cate[5]; const float* kern[5];
  for (int i=0;i<5;i++){ cate[i]=(const float*)d_in[2*i]; kern[i]=(const float*)d_in[2*i+1]; }
  const float* seg = (const float*)d_in[10];
  char* ws = (char*)d_ws;
  float* out = (float*)d_out;

  const bool mfma = (ws_size >= WS_MFMA);

  float* kf      = (float*)(ws + (mfma ? B_KF   : F_KF));
  float* scores  = (float*)(ws + (mfma ? B_SC   : F_SC));
  float* summ    = (float*)(ws + (mfma ? B_SM   : F_SM));
  float* cs      = (float*)(ws + (mfma ? B_CS   : F_CS));
  unsigned long long* bits = (unsigned long long*)(ws + (mfma ? B_BIT : F_BIT));
  float* spp     = (float*)(ws + (mfma ? B_SPP  : F_SPP));
  int*   tidx    = (int*)(ws + (mfma ? B_TIDX : F_TIDX));
  float* tsc     = (float*)(ws + (mfma ? B_TSC  : F_TSC));
  float* smt     = (float*)(ws + (mfma ? B_SMT  : F_SMT));
  float* iou     = (float*)(ws + (mfma ? B_IOU  : F_IOU));
  float* comp    = (float*)(ws + (mfma ? B_COMP : F_COMP));
  float* nms     = (float*)(ws + (mfma ? B_NMS  : F_NMS));
  int*   sel     = (int*)(ws + (mfma ? B_SEL  : F_SEL));
  float* selp    = (float*)(ws + (mfma ? B_SELP : F_SELP));

  k0a_gather<<<dim3(800,5), 256, 0, stream>>>(cate[0],cate[1],cate[2],cate[3],cate[4],
                                    kern[0],kern[1],kern[2],kern[3],kern[4], kf, scores);
  if (mfma) {
    _Float16* Af = (_Float16*)(ws + B_AFR);
    _Float16* Bf = (_Float16*)(ws + B_BFR);
    k0b_afrag<<<31*4*1024/256, 256, 0, stream>>>(kf, Af);
    k0c_bfrag<<<128*4*1024/256, 256, 0, stream>>>(seg, Bf);
    k1_mfma  <<<dim3(31, 128), 256, 0, stream>>>(Af, Bf, bits, spp);
    k2_cscore<<<M_CELLS/4, 256, 0, stream>>>(bits, spp, scores, summ, cs, 128, M_PAD);
  } else {
    k1_gemm  <<<dim3(64,121), 256, 0, stream>>>(kf, seg, bits, spp);
    k2_cscore<<<M_CELLS/4, 256, 0, stream>>>(bits, spp, scores, summ, cs, 64, M_CELLS);
  }
  k3_top500<<<1, 1024, 0, stream>>>(cs, summ, tidx, tsc, smt);
  k4_iou   <<<dim3(32,32), 256, 0, stream>>>(bits, tidx, smt, iou);
  k5_comp  <<<1, 512, 0, stream>>>(iou, comp);
  k6_decay <<<1, 512, 0, stream>>>(iou, comp, tsc, nms);
  k7_top30 <<<1, 256, 0, stream>>>(nms, tidx, sel, out);
  k8_selp  <<<dim3(64,30), 256, 0, stream>>>(kf, seg, sel, selp);
  k9_bbox  <<<30, 1024, 0, stream>>>(selp, out);
}